// Round 6
// baseline (232.026 us; speedup 1.0000x reference)
//
#include <hip/hip_runtime.h>
#include <math.h>

#define T_ 4096
#define D_ 128
#define NTOK 8192
#define CHUNK 64
#define NCB 64        // chunks per batch
#define NCH 128       // total chunks
#define NBLK 256
#define LN_EPS 1e-5f
#define EPS_ATTN 1e-6f

typedef __attribute__((ext_vector_type(8))) short bf16x8;
typedef __attribute__((ext_vector_type(4))) short bf16x4;
typedef __attribute__((ext_vector_type(4))) float f32x4;

__device__ inline short f2bf(float f) {
  unsigned u = __builtin_bit_cast(unsigned, f);
  u += 0x7fffu + ((u >> 16) & 1u);
  return (short)(u >> 16);
}
__device__ inline float bf2f(short s) {
  unsigned u = ((unsigned)(unsigned short)s) << 16;
  return __builtin_bit_cast(float, u);
}
__device__ inline float phi_(float x) { return x > 0.f ? x + 1.f : __expf(x); }

// one-shot grid barrier: counter pre-zeroed by hipMemsetAsync each launch.
// Writer side: __threadfence (agent-scope release, flushes this XCD's dirty L2)
// then device-scope atomicAdd arrival. Reader: spin on atomic read, then
// __threadfence (acquire, invalidates local caches). All blocks co-resident:
// 62KB LDS/block -> 2 blocks/CU capacity, grid=256=1*CU count.
__device__ inline void gbar(unsigned* cnt) {
  __syncthreads();
  if (threadIdx.x == 0) {
    __threadfence();
    atomicAdd(cnt, 1u);
    while (atomicAdd(cnt, 0u) < NBLK) __builtin_amdgcn_s_sleep(1);
    __threadfence();
  }
  __syncthreads();
}

struct Params {
  const float *tokens, *Wq, *Wk, *Wv, *Wg, *bg, *Wo, *g1, *b1, *g2, *b2;
  short *xb, *WT, *Qp, *Kp, *KpT, *VgT, *attn, *KVTb;
  float *KVT, *Ksum, *out;
  unsigned *bar;
};

struct S0 { float tile[32][33]; };
struct S1 { short xs[64][136]; short wsd[128][136]; };
struct S2 { short vgl[128][72]; short kpl[64][72]; float ksp[64][5]; };
struct S4 { short at[64][200]; short bt[64][200];
            float ksl[128]; float rsl[64]; float dpart[64][4]; float denl[64]; };
struct S5 { short al[32][136]; short wl[128][136]; float tl[32][132];
            float suml[32][2]; float ssql[32][2]; float meanl[32]; float rstdl[32];
            float gl[128]; float bl2[128]; };

__global__ __launch_bounds__(256, 1) void mega(Params P) {
  __shared__ union { S0 s0; S1 s1; S2 s2; S4 s4; S5 s5; } sm;
  const int tid = threadIdx.x;
  const int bid = blockIdx.x;
  const int gsz = gridDim.x;
  const int w = tid >> 6, l = tid & 63, i = l & 15, q = l >> 4;

  // ================= stage 0: weight cvt+transpose (u<5) || LN1 (u>=5) ==========
  for (int u = bid; u < 133; u += gsz) {
    if (u < 5) {
      const float* W = u==0?P.Wq : u==1?P.Wk : u==2?P.Wv : u==3?P.Wg : P.Wo;
      short* dst = P.WT + u*16384;
      const int r = tid >> 3, c4 = (tid & 7)*4;
      for (int tt = 0; tt < 16; ++tt) {
        const int k0 = (tt >> 2)*32, n0 = (tt & 3)*32;
        __syncthreads();
        const float4 v = *(const float4*)&W[(k0 + r)*D_ + n0 + c4];
        sm.s0.tile[r][c4] = v.x; sm.s0.tile[r][c4+1] = v.y;
        sm.s0.tile[r][c4+2] = v.z; sm.s0.tile[r][c4+3] = v.w;
        __syncthreads();
        bf16x4 o;
        o.x = f2bf(sm.s0.tile[c4+0][r]); o.y = f2bf(sm.s0.tile[c4+1][r]);
        o.z = f2bf(sm.s0.tile[c4+2][r]); o.w = f2bf(sm.s0.tile[c4+3][r]);
        *(bf16x4*)&dst[(n0 + r)*D_ + k0 + c4] = o;
      }
    } else {
      const int t0 = (u - 5)*64;
      const int half = l >> 5;
      const int c4 = (l & 31)*4;
      const float4 gg = *(const float4*)&P.g1[c4];
      const float4 bb = *(const float4*)&P.b1[c4];
      #pragma unroll
      for (int it = 0; it < 8; ++it) {
        const int t = t0 + w*16 + it*2 + half;
        const float4 v = *(const float4*)&P.tokens[t*D_ + c4];
        float s = v.x+v.y+v.z+v.w;
        float qq = v.x*v.x+v.y*v.y+v.z*v.z+v.w*v.w;
        #pragma unroll
        for (int off = 1; off < 32; off <<= 1) {
          s += __shfl_xor(s, off); qq += __shfl_xor(qq, off);
        }
        const float mean = s*(1.f/D_);
        const float r2 = rsqrtf(qq*(1.f/D_) - mean*mean + LN_EPS);
        bf16x4 o;
        o.x = f2bf((v.x-mean)*r2*gg.x + bb.x);
        o.y = f2bf((v.y-mean)*r2*gg.y + bb.y);
        o.z = f2bf((v.z-mean)*r2*gg.z + bb.z);
        o.w = f2bf((v.w-mean)*r2*gg.w + bb.w);
        *(bf16x4*)&P.xb[t*D_ + c4] = o;
      }
    }
  }
  gbar(P.bar + 0);

  // ================= stage 1: QKVG GEMMs ==========
  for (int u = bid; u < 256; u += gsz) {
    if (u < 128) {
      const int y = u >> 6, p = u & 63;
      const short* Wb = P.WT + y*16384;
      for (int v = tid; v < 2048; v += 256) {
        const int n = v >> 4, c8 = (v & 15)*8;
        *(bf16x8*)&sm.s1.wsd[n][c8] = *(const bf16x8*)&Wb[n*D_ + c8];
      }
      for (int half = 0; half < 2; ++half) {
        const int m0 = (p*2 + half)*64;
        __syncthreads();
        for (int v = tid; v < 1024; v += 256) {
          const int r = v >> 4, c8 = (v & 15)*8;
          *(bf16x8*)&sm.s1.xs[r][c8] = *(const bf16x8*)&P.xb[(m0+r)*D_ + c8];
        }
        __syncthreads();
        f32x4 acc[4][2];
        #pragma unroll
        for (int mt = 0; mt < 4; ++mt)
          #pragma unroll
          for (int nt = 0; nt < 2; ++nt) acc[mt][nt] = (f32x4){0.f,0.f,0.f,0.f};
        #pragma unroll
        for (int kk = 0; kk < 4; ++kk) {
          bf16x8 a[4], bfr[2];
          #pragma unroll
          for (int mt = 0; mt < 4; ++mt) a[mt] = *(const bf16x8*)&sm.s1.xs[mt*16+i][kk*32+q*8];
          #pragma unroll
          for (int nt = 0; nt < 2; ++nt) bfr[nt] = *(const bf16x8*)&sm.s1.wsd[w*32+nt*16+i][kk*32+q*8];
          #pragma unroll
          for (int mt = 0; mt < 4; ++mt)
            #pragma unroll
            for (int nt = 0; nt < 2; ++nt)
              acc[mt][nt] = __builtin_amdgcn_mfma_f32_16x16x32_bf16(a[mt], bfr[nt], acc[mt][nt], 0, 0, 0);
        }
        if (y == 0) {
          #pragma unroll
          for (int mt = 0; mt < 4; ++mt)
            #pragma unroll
            for (int nt = 0; nt < 2; ++nt) {
              const int h = w*32 + nt*16 + i;
              #pragma unroll
              for (int r = 0; r < 4; ++r)
                P.Qp[(m0 + mt*16 + 4*q + r)*D_ + h] = f2bf(phi_(acc[mt][nt][r]));
            }
        } else {
          #pragma unroll
          for (int mt = 0; mt < 4; ++mt)
            #pragma unroll
            for (int nt = 0; nt < 2; ++nt) {
              const int h = w*32 + nt*16 + i;
              const int t0 = m0 + mt*16 + 4*q;
              bf16x4 o;
              #pragma unroll
              for (int r = 0; r < 4; ++r) {
                const short bv = f2bf(phi_(acc[mt][nt][r]));
                P.Kp[(t0+r)*D_ + h] = bv;
                o[r] = bv;
              }
              *(bf16x4*)&P.KpT[h*NTOK + t0] = o;
            }
        }
      }
    } else {
      const int m0 = (u - 128)*64;
      __syncthreads();
      for (int v = tid; v < 1024; v += 256) {
        const int r = v >> 4, c8 = (v & 15)*8;
        *(bf16x8*)&sm.s1.xs[r][c8] = *(const bf16x8*)&P.xb[(m0+r)*D_ + c8];
      }
      const short* Wvb = P.WT + 2*16384;
      for (int v = tid; v < 2048; v += 256) {
        const int n = v >> 4, c8 = (v & 15)*8;
        *(bf16x8*)&sm.s1.wsd[n][c8] = *(const bf16x8*)&Wvb[n*D_ + c8];
      }
      __syncthreads();
      f32x4 accv[4][2], accg[4][2];
      #pragma unroll
      for (int mt = 0; mt < 4; ++mt)
        #pragma unroll
        for (int nt = 0; nt < 2; ++nt) {
          accv[mt][nt] = (f32x4){0.f,0.f,0.f,0.f};
          accg[mt][nt] = (f32x4){0.f,0.f,0.f,0.f};
        }
      #pragma unroll
      for (int kk = 0; kk < 4; ++kk) {
        bf16x8 a[4], bfr[2];
        #pragma unroll
        for (int mt = 0; mt < 4; ++mt) a[mt] = *(const bf16x8*)&sm.s1.xs[mt*16+i][kk*32+q*8];
        #pragma unroll
        for (int nt = 0; nt < 2; ++nt) bfr[nt] = *(const bf16x8*)&sm.s1.wsd[w*32+nt*16+i][kk*32+q*8];
        #pragma unroll
        for (int mt = 0; mt < 4; ++mt)
          #pragma unroll
          for (int nt = 0; nt < 2; ++nt)
            accv[mt][nt] = __builtin_amdgcn_mfma_f32_16x16x32_bf16(a[mt], bfr[nt], accv[mt][nt], 0, 0, 0);
      }
      __syncthreads();
      const short* Wgb = P.WT + 3*16384;
      for (int v = tid; v < 2048; v += 256) {
        const int n = v >> 4, c8 = (v & 15)*8;
        *(bf16x8*)&sm.s1.wsd[n][c8] = *(const bf16x8*)&Wgb[n*D_ + c8];
      }
      __syncthreads();
      #pragma unroll
      for (int kk = 0; kk < 4; ++kk) {
        bf16x8 a[4], bfr[2];
        #pragma unroll
        for (int mt = 0; mt < 4; ++mt) a[mt] = *(const bf16x8*)&sm.s1.xs[mt*16+i][kk*32+q*8];
        #pragma unroll
        for (int nt = 0; nt < 2; ++nt) bfr[nt] = *(const bf16x8*)&sm.s1.wsd[w*32+nt*16+i][kk*32+q*8];
        #pragma unroll
        for (int mt = 0; mt < 4; ++mt)
          #pragma unroll
          for (int nt = 0; nt < 2; ++nt)
            accg[mt][nt] = __builtin_amdgcn_mfma_f32_16x16x32_bf16(a[mt], bfr[nt], accg[mt][nt], 0, 0, 0);
      }
      #pragma unroll
      for (int mt = 0; mt < 4; ++mt)
        #pragma unroll
        for (int nt = 0; nt < 2; ++nt) {
          const int h = w*32 + nt*16 + i;
          const int t0 = m0 + mt*16 + 4*q;
          const float bgd = P.bg[h];
          bf16x4 o;
          #pragma unroll
          for (int r = 0; r < 4; ++r) {
            const float gv = 1.f/(1.f + __expf(-(accg[mt][nt][r] + bgd)));
            o[r] = f2bf(accv[mt][nt][r] * gv);
          }
          *(bf16x4*)&P.VgT[h*NTOK + t0] = o;
        }
    }
  }
  gbar(P.bar + 1);

  // ================= stage 2: per-chunk KV^T + Ksum ==========
  for (int u = bid; u < 256; u += gsz) {
    const int c = u >> 1, hh = u & 1;
    const int tb = c*CHUNK;
    __syncthreads();
    for (int v = tid; v < 1024; v += 256) {
      const int d = v >> 3, c8 = (v & 7)*8;
      *(bf16x8*)&sm.s2.vgl[d][c8] = *(const bf16x8*)&P.VgT[d*NTOK + tb + c8];
    }
    for (int v = tid; v < 512; v += 256) {
      const int h = v >> 3, c8 = (v & 7)*8;
      *(bf16x8*)&sm.s2.kpl[h][c8] = *(const bf16x8*)&P.KpT[(hh*64+h)*NTOK + tb + c8];
    }
    __syncthreads();
    f32x4 acc[2][4];
    #pragma unroll
    for (int mt = 0; mt < 2; ++mt)
      #pragma unroll
      for (int nt = 0; nt < 4; ++nt) acc[mt][nt] = (f32x4){0.f,0.f,0.f,0.f};
    #pragma unroll
    for (int kk = 0; kk < 2; ++kk) {
      bf16x8 a[2], bb[4];
      #pragma unroll
      for (int mt = 0; mt < 2; ++mt) a[mt] = *(const bf16x8*)&sm.s2.vgl[(2*w+mt)*16+i][kk*32+q*8];
      #pragma unroll
      for (int nt = 0; nt < 4; ++nt) bb[nt] = *(const bf16x8*)&sm.s2.kpl[nt*16+i][kk*32+q*8];
      #pragma unroll
      for (int mt = 0; mt < 2; ++mt)
        #pragma unroll
        for (int nt = 0; nt < 4; ++nt)
          acc[mt][nt] = __builtin_amdgcn_mfma_f32_16x16x32_bf16(a[mt], bb[nt], acc[mt][nt], 0, 0, 0);
    }
    float* KVc = P.KVT + (size_t)c*16384;
    #pragma unroll
    for (int mt = 0; mt < 2; ++mt)
      #pragma unroll
      for (int nt = 0; nt < 4; ++nt)
        #pragma unroll
        for (int r = 0; r < 4; ++r)
          KVc[((2*w+mt)*16 + 4*q + r)*D_ + hh*64 + nt*16 + i] = acc[mt][nt][r];
    {
      const int h = tid >> 2, part = tid & 3;
      float s = 0.f;
      #pragma unroll
      for (int t = 0; t < 16; ++t) s += bf2f(sm.s2.kpl[h][part*16 + t]);
      sm.s2.ksp[h][part] = s;
    }
    __syncthreads();
    if (tid < 64)
      P.Ksum[c*D_ + hh*64 + tid] = sm.s2.ksp[tid][0]+sm.s2.ksp[tid][1]+sm.s2.ksp[tid][2]+sm.s2.ksp[tid][3];
  }
  gbar(P.bar + 2);

  // ================= stage 3: exclusive chunk prefix ==========
  for (int u = bid; u < 129; u += gsz) {
    if (u < 128) {
      const int b = u >> 6;
      const int e = (u & 63)*256 + tid;
      const size_t base = (size_t)b*NCB*16384 + e;
      float run = 0.f;
      #pragma unroll 8
      for (int c = 0; c < NCB; ++c) {
        const float v = P.KVT[base + (size_t)c*16384];
        P.KVTb[base + (size_t)c*16384] = f2bf(run);
        run += v;
      }
    } else {
      const int b = tid >> 7, h = tid & 127;
      float run = 0.f;
      #pragma unroll 8
      for (int c = 0; c < NCB; ++c) {
        const int idx = (b*NCB + c)*D_ + h;
        const float v = P.Ksum[idx];
        P.Ksum[idx] = run;
        run += v;
      }
    }
  }
  gbar(P.bar + 3);

  // ================= stage 4: scores + attnout fused ==========
  for (int u = bid; u < 256; u += gsz) {
    const int c = u >> 1, dh = u & 1;
    const int tb = c*CHUNK;
    __syncthreads();
    for (int v = tid; v < 1024; v += 256) {
      const int t = v >> 4, c8 = (v & 15)*8;
      *(bf16x8*)&sm.s4.at[t][64 + c8] = *(const bf16x8*)&P.Qp[(tb+t)*D_ + c8];
      *(bf16x8*)&sm.s4.bt[t][c8]      = *(const bf16x8*)&P.Kp[(tb+t)*D_ + c8];
    }
    if (tid < 128) sm.s4.ksl[tid] = P.Ksum[c*D_ + tid];
    __syncthreads();
    {
      f32x4 acc[4];
      #pragma unroll
      for (int nt = 0; nt < 4; ++nt) acc[nt] = (f32x4){0.f,0.f,0.f,0.f};
      #pragma unroll
      for (int kk = 0; kk < 4; ++kk) {
        bf16x8 a = *(const bf16x8*)&sm.s4.at[w*16+i][64 + kk*32+q*8];
        for (int nt = 0; nt <= w; ++nt) {
          bf16x8 bb = *(const bf16x8*)&sm.s4.bt[nt*16+i][kk*32+q*8];
          acc[nt] = __builtin_amdgcn_mfma_f32_16x16x32_bf16(a, bb, acc[nt], 0, 0, 0);
        }
      }
      float rs[4] = {0.f,0.f,0.f,0.f};
      #pragma unroll
      for (int nt = 0; nt < 4; ++nt)
        #pragma unroll
        for (int r = 0; r < 4; ++r) {
          const int t = w*16 + 4*q + r;
          const int s = nt*16 + i;
          const float v = (nt <= w && s <= t) ? acc[nt][r] : 0.f;
          rs[r] += v;
          sm.s4.at[t][s] = f2bf(v);
        }
      #pragma unroll
      for (int r = 0; r < 4; ++r) {
        #pragma unroll
        for (int off = 1; off < 16; off <<= 1) rs[r] += __shfl_xor(rs[r], off);
      }
      if (i == 0) {
        #pragma unroll
        for (int r = 0; r < 4; ++r) sm.s4.rsl[w*16 + 4*q + r] = rs[r];
      }
    }
    {
      const int t = tid >> 2, part = tid & 3;
      float dot = 0.f;
      #pragma unroll
      for (int h = 0; h < 32; ++h)
        dot += bf2f(sm.s4.at[t][64 + part*32 + h]) * sm.s4.ksl[part*32 + h];
      sm.s4.dpart[t][part] = dot;
    }
    __syncthreads();
    if (tid < 64)
      sm.s4.denl[tid] = fmaxf(sm.s4.rsl[tid] + sm.s4.dpart[tid][0]+sm.s4.dpart[tid][1]
                              +sm.s4.dpart[tid][2]+sm.s4.dpart[tid][3], EPS_ATTN);
    for (int v = tid; v < 512; v += 256) {
      const int dd = v >> 3, c8 = (v & 7)*8;
      *(bf16x8*)&sm.s4.bt[dd][c8] = *(const bf16x8*)&P.VgT[(dh*64+dd)*NTOK + tb + c8];
    }
    for (int v = tid; v < 1024; v += 256) {
      const int dd = v >> 4, c8 = (v & 15)*8;
      *(bf16x8*)&sm.s4.bt[dd][64 + c8] = *(const bf16x8*)&P.KVTb[(size_t)c*16384 + (dh*64+dd)*D_ + c8];
    }
    __syncthreads();
    f32x4 acc2[4];
    #pragma unroll
    for (int nt = 0; nt < 4; ++nt) acc2[nt] = (f32x4){0.f,0.f,0.f,0.f};
    #pragma unroll
    for (int kk = 0; kk < 6; ++kk) {
      bf16x8 a = *(const bf16x8*)&sm.s4.at[w*16+i][kk*32+q*8];
      #pragma unroll
      for (int nt = 0; nt < 4; ++nt) {
        bf16x8 bb = *(const bf16x8*)&sm.s4.bt[nt*16+i][kk*32+q*8];
        acc2[nt] = __builtin_amdgcn_mfma_f32_16x16x32_bf16(a, bb, acc2[nt], 0, 0, 0);
      }
    }
    #pragma unroll
    for (int r = 0; r < 4; ++r) {
      const int t = w*16 + 4*q + r;
      const float inv = 1.f / sm.s4.denl[t];
      #pragma unroll
      for (int nt = 0; nt < 4; ++nt)
        P.attn[(size_t)(tb+t)*D_ + dh*64 + nt*16 + i] = f2bf(acc2[nt][r] * inv);
    }
  }
  gbar(P.bar + 4);

  // ================= stage 5: out = LN2(tokens + 0.1*(attn@Wo)) ==========
  for (int u = bid; u < 256; u += gsz) {
    const int m0 = u*32;
    __syncthreads();
    for (int v = tid; v < 512; v += 256) {
      const int t = v >> 4, c8 = (v & 15)*8;
      *(bf16x8*)&sm.s5.al[t][c8] = *(const bf16x8*)&P.attn[(m0+t)*D_ + c8];
    }
    const short* WoT = P.WT + 4*16384;
    for (int v = tid; v < 2048; v += 256) {
      const int n = v >> 4, c8 = (v & 15)*8;
      *(bf16x8*)&sm.s5.wl[n][c8] = *(const bf16x8*)&WoT[n*D_ + c8];
    }
    for (int v = tid; v < 1024; v += 256) {
      const int t = v >> 5, c4 = (v & 31)*4;
      *(float4*)&sm.s5.tl[t][c4] = *(const float4*)&P.tokens[(m0+t)*D_ + c4];
    }
    if (tid < 128) { sm.s5.gl[tid] = P.g2[tid]; sm.s5.bl2[tid] = P.b2[tid]; }
    __syncthreads();
    const int mt = w >> 1, nh = w & 1;
    f32x4 acc[4];
    #pragma unroll
    for (int j = 0; j < 4; ++j) acc[j] = (f32x4){0.f,0.f,0.f,0.f};
    #pragma unroll
    for (int kk = 0; kk < 4; ++kk) {
      bf16x8 a = *(const bf16x8*)&sm.s5.al[mt*16+i][kk*32+q*8];
      #pragma unroll
      for (int j = 0; j < 4; ++j) {
        bf16x8 bb = *(const bf16x8*)&sm.s5.wl[(nh*4+j)*16+i][kk*32+q*8];
        acc[j] = __builtin_amdgcn_mfma_f32_16x16x32_bf16(a, bb, acc[j], 0, 0, 0);
      }
    }
    float p[4][4], ps[4], qs[4];
    #pragma unroll
    for (int r = 0; r < 4; ++r) {
      const int t = mt*16 + 4*q + r;
      ps[r] = 0.f; qs[r] = 0.f;
      #pragma unroll
      for (int j = 0; j < 4; ++j) {
        const int col = nh*64 + j*16 + i;
        const float v = sm.s5.tl[t][col] + 0.1f*acc[j][r];
        p[r][j] = v; ps[r] += v; qs[r] += v*v;
      }
    }
    #pragma unroll
    for (int r = 0; r < 4; ++r) {
      #pragma unroll
      for (int off = 1; off < 16; off <<= 1) {
        ps[r] += __shfl_xor(ps[r], off);
        qs[r] += __shfl_xor(qs[r], off);
      }
    }
    if (i == 0) {
      #pragma unroll
      for (int r = 0; r < 4; ++r) {
        sm.s5.suml[mt*16+4*q+r][nh] = ps[r];
        sm.s5.ssql[mt*16+4*q+r][nh] = qs[r];
      }
    }
    __syncthreads();
    if (tid < 32) {
      const float s = sm.s5.suml[tid][0] + sm.s5.suml[tid][1];
      const float qq = sm.s5.ssql[tid][0] + sm.s5.ssql[tid][1];
      const float mean = s*(1.f/D_);
      sm.s5.meanl[tid] = mean;
      sm.s5.rstdl[tid] = rsqrtf(qq*(1.f/D_) - mean*mean + LN_EPS);
    }
    __syncthreads();
    #pragma unroll
    for (int r = 0; r < 4; ++r) {
      const int t = mt*16 + 4*q + r;
      const float mean = sm.s5.meanl[t], rr = sm.s5.rstdl[t];
      #pragma unroll
      for (int j = 0; j < 4; ++j) {
        const int col = nh*64 + j*16 + i;
        P.out[(m0+t)*D_ + col] = (p[r][j]-mean)*rr*sm.s5.gl[col] + sm.s5.bl2[col];
      }
    }
  }
}

extern "C" void kernel_launch(void* const* d_in, const int* in_sizes, int n_in,
                              void* d_out, int out_size, void* d_ws, size_t ws_size,
                              hipStream_t stream) {
  char* base = (char*)d_ws;
  Params P;
  P.tokens = (const float*)d_in[0];
  P.Wq = (const float*)d_in[1];  P.Wk = (const float*)d_in[2];
  P.Wv = (const float*)d_in[3];  P.Wg = (const float*)d_in[4];
  P.bg = (const float*)d_in[5];  P.Wo = (const float*)d_in[6];
  P.g1 = (const float*)d_in[7];  P.b1 = (const float*)d_in[8];
  P.g2 = (const float*)d_in[9];  P.b2 = (const float*)d_in[10];
  P.xb   = (short*)(base);                 // 2MB
  P.Qp   = (short*)(base + (2u<<20));      // 2MB
  P.Kp   = (short*)(base + (4u<<20));      // 2MB
  P.KpT  = (short*)(base + (6u<<20));      // 2MB
  P.VgT  = (short*)(base + (8u<<20));      // 2MB
  P.attn = (short*)(base + (10u<<20));     // 2MB
  P.KVTb = (short*)(base + (12u<<20));     // 4MB
  P.KVT  = (float*)(base + (16u<<20));     // 8MB
  P.WT   = (short*)(base + (24u<<20));     // 160KB
  P.Ksum = (float*)(base + (25u<<20));     // 64KB
  P.bar  = (unsigned*)(base + (25u<<20) + (128u<<10)); // 5 counters
  P.out  = (float*)d_out;

  hipMemsetAsync(P.bar, 0, 8*sizeof(unsigned), stream);
  mega<<<dim3(NBLK), dim3(256), 0, stream>>>(P);
}

// Round 7
// 193.126 us; speedup vs baseline: 1.2014x; 1.2014x over previous
//
#include <hip/hip_runtime.h>
#include <math.h>

#define T_ 4096
#define D_ 128
#define NTOK 8192
#define CHUNK 64
#define NCB 64        // chunks per batch
#define NCH 128       // total chunks
#define NBLK 256
#define LN_EPS 1e-5f
#define EPS_ATTN 1e-6f

typedef __attribute__((ext_vector_type(8))) short bf16x8;
typedef __attribute__((ext_vector_type(4))) short bf16x4;
typedef __attribute__((ext_vector_type(4))) float f32x4;

__device__ inline short f2bf(float f) {
  unsigned u = __builtin_bit_cast(unsigned, f);
  u += 0x7fffu + ((u >> 16) & 1u);
  return (short)(u >> 16);
}
__device__ inline float bf2f(short s) {
  unsigned u = ((unsigned)(unsigned short)s) << 16;
  return __builtin_bit_cast(float, u);
}
__device__ inline float phi_(float x) { return x > 0.f ? x + 1.f : __expf(x); }

// one-shot grid barrier, counters pre-zeroed by hipMemsetAsync each launch.
// Arrival: ONE device-scope RMW per block with release semantics (waitcnt +
// L2 writeback precede the add -> all this block's stores visible at L3).
// Poll: relaxed device-scope atomic LOADS (concurrent, L3-broadcast, no RMW
// serialization) + s_sleep backoff; acquire fence after -> invalidate stale L2.
// All 256 blocks co-resident (62KB LDS < 160KB -> >=1 block/CU, grid == CUs).
__device__ inline void gbar(unsigned* cnt) {
  __syncthreads();   // drains each wave's vmcnt before s_barrier (HIP semantics)
  if (threadIdx.x == 0) {
    __hip_atomic_fetch_add(cnt, 1u, __ATOMIC_RELEASE, __HIP_MEMORY_SCOPE_AGENT);
    while (__hip_atomic_load(cnt, __ATOMIC_RELAXED, __HIP_MEMORY_SCOPE_AGENT) < NBLK)
      __builtin_amdgcn_s_sleep(16);
    __builtin_amdgcn_fence(__ATOMIC_ACQUIRE, "agent");
  }
  __syncthreads();
}

struct Params {
  const float *tokens, *Wq, *Wk, *Wv, *Wg, *bg, *Wo, *g1, *b1, *g2, *b2;
  short *xb, *WT, *Qp, *Kp, *KpT, *VgT, *attn, *KVTb;
  float *KVT, *Ksum, *out;
  unsigned *bar;
};

struct S0 { float tile[32][33]; };
struct S1 { short xs[64][136]; short wsd[128][136]; };
struct S2 { short vgl[128][72]; short kpl[64][72]; float ksp[64][5]; };
struct S4 { short at[64][200]; short bt[64][200];
            float ksl[128]; float rsl[64]; float dpart[64][4]; float denl[64]; };
struct S5 { short al[32][136]; short wl[128][136]; float tl[32][132];
            float suml[32][2]; float ssql[32][2]; float meanl[32]; float rstdl[32];
            float gl[128]; float bl2[128]; };

__global__ __launch_bounds__(256, 1) void mega(Params P) {
  __shared__ union { S0 s0; S1 s1; S2 s2; S4 s4; S5 s5; } sm;
  const int tid = threadIdx.x;
  const int bid = blockIdx.x;
  const int gsz = gridDim.x;
  const int w = tid >> 6, l = tid & 63, i = l & 15, q = l >> 4;

  // ================= stage 0: weight cvt+transpose (u<5) || LN1 (u>=5) ==========
  for (int u = bid; u < 133; u += gsz) {
    if (u < 5) {
      const float* W = u==0?P.Wq : u==1?P.Wk : u==2?P.Wv : u==3?P.Wg : P.Wo;
      short* dst = P.WT + u*16384;
      const int r = tid >> 3, c4 = (tid & 7)*4;
      for (int tt = 0; tt < 16; ++tt) {
        const int k0 = (tt >> 2)*32, n0 = (tt & 3)*32;
        __syncthreads();
        const float4 v = *(const float4*)&W[(k0 + r)*D_ + n0 + c4];
        sm.s0.tile[r][c4] = v.x; sm.s0.tile[r][c4+1] = v.y;
        sm.s0.tile[r][c4+2] = v.z; sm.s0.tile[r][c4+3] = v.w;
        __syncthreads();
        bf16x4 o;
        o.x = f2bf(sm.s0.tile[c4+0][r]); o.y = f2bf(sm.s0.tile[c4+1][r]);
        o.z = f2bf(sm.s0.tile[c4+2][r]); o.w = f2bf(sm.s0.tile[c4+3][r]);
        *(bf16x4*)&dst[(n0 + r)*D_ + k0 + c4] = o;
      }
    } else {
      const int t0 = (u - 5)*64;
      const int half = l >> 5;
      const int c4 = (l & 31)*4;
      const float4 gg = *(const float4*)&P.g1[c4];
      const float4 bb = *(const float4*)&P.b1[c4];
      #pragma unroll
      for (int it = 0; it < 8; ++it) {
        const int t = t0 + w*16 + it*2 + half;
        const float4 v = *(const float4*)&P.tokens[t*D_ + c4];
        float s = v.x+v.y+v.z+v.w;
        float qq = v.x*v.x+v.y*v.y+v.z*v.z+v.w*v.w;
        #pragma unroll
        for (int off = 1; off < 32; off <<= 1) {
          s += __shfl_xor(s, off); qq += __shfl_xor(qq, off);
        }
        const float mean = s*(1.f/D_);
        const float r2 = rsqrtf(qq*(1.f/D_) - mean*mean + LN_EPS);
        bf16x4 o;
        o.x = f2bf((v.x-mean)*r2*gg.x + bb.x);
        o.y = f2bf((v.y-mean)*r2*gg.y + bb.y);
        o.z = f2bf((v.z-mean)*r2*gg.z + bb.z);
        o.w = f2bf((v.w-mean)*r2*gg.w + bb.w);
        *(bf16x4*)&P.xb[t*D_ + c4] = o;
      }
    }
  }
  gbar(P.bar + 0);

  // ================= stage 1: QKVG GEMMs ==========
  for (int u = bid; u < 256; u += gsz) {
    if (u < 128) {
      const int y = u >> 6, p = u & 63;
      const short* Wb = P.WT + y*16384;
      for (int v = tid; v < 2048; v += 256) {
        const int n = v >> 4, c8 = (v & 15)*8;
        *(bf16x8*)&sm.s1.wsd[n][c8] = *(const bf16x8*)&Wb[n*D_ + c8];
      }
      for (int half = 0; half < 2; ++half) {
        const int m0 = (p*2 + half)*64;
        __syncthreads();
        for (int v = tid; v < 1024; v += 256) {
          const int r = v >> 4, c8 = (v & 15)*8;
          *(bf16x8*)&sm.s1.xs[r][c8] = *(const bf16x8*)&P.xb[(m0+r)*D_ + c8];
        }
        __syncthreads();
        f32x4 acc[4][2];
        #pragma unroll
        for (int mt = 0; mt < 4; ++mt)
          #pragma unroll
          for (int nt = 0; nt < 2; ++nt) acc[mt][nt] = (f32x4){0.f,0.f,0.f,0.f};
        #pragma unroll
        for (int kk = 0; kk < 4; ++kk) {
          bf16x8 a[4], bfr[2];
          #pragma unroll
          for (int mt = 0; mt < 4; ++mt) a[mt] = *(const bf16x8*)&sm.s1.xs[mt*16+i][kk*32+q*8];
          #pragma unroll
          for (int nt = 0; nt < 2; ++nt) bfr[nt] = *(const bf16x8*)&sm.s1.wsd[w*32+nt*16+i][kk*32+q*8];
          #pragma unroll
          for (int mt = 0; mt < 4; ++mt)
            #pragma unroll
            for (int nt = 0; nt < 2; ++nt)
              acc[mt][nt] = __builtin_amdgcn_mfma_f32_16x16x32_bf16(a[mt], bfr[nt], acc[mt][nt], 0, 0, 0);
        }
        if (y == 0) {
          #pragma unroll
          for (int mt = 0; mt < 4; ++mt)
            #pragma unroll
            for (int nt = 0; nt < 2; ++nt) {
              const int h = w*32 + nt*16 + i;
              #pragma unroll
              for (int r = 0; r < 4; ++r)
                P.Qp[(m0 + mt*16 + 4*q + r)*D_ + h] = f2bf(phi_(acc[mt][nt][r]));
            }
        } else {
          #pragma unroll
          for (int mt = 0; mt < 4; ++mt)
            #pragma unroll
            for (int nt = 0; nt < 2; ++nt) {
              const int h = w*32 + nt*16 + i;
              const int t0 = m0 + mt*16 + 4*q;
              bf16x4 o;
              #pragma unroll
              for (int r = 0; r < 4; ++r) {
                const short bv = f2bf(phi_(acc[mt][nt][r]));
                P.Kp[(t0+r)*D_ + h] = bv;
                o[r] = bv;
              }
              *(bf16x4*)&P.KpT[h*NTOK + t0] = o;
            }
        }
      }
    } else {
      const int m0 = (u - 128)*64;
      __syncthreads();
      for (int v = tid; v < 1024; v += 256) {
        const int r = v >> 4, c8 = (v & 15)*8;
        *(bf16x8*)&sm.s1.xs[r][c8] = *(const bf16x8*)&P.xb[(m0+r)*D_ + c8];
      }
      const short* Wvb = P.WT + 2*16384;
      for (int v = tid; v < 2048; v += 256) {
        const int n = v >> 4, c8 = (v & 15)*8;
        *(bf16x8*)&sm.s1.wsd[n][c8] = *(const bf16x8*)&Wvb[n*D_ + c8];
      }
      __syncthreads();
      f32x4 accv[4][2], accg[4][2];
      #pragma unroll
      for (int mt = 0; mt < 4; ++mt)
        #pragma unroll
        for (int nt = 0; nt < 2; ++nt) {
          accv[mt][nt] = (f32x4){0.f,0.f,0.f,0.f};
          accg[mt][nt] = (f32x4){0.f,0.f,0.f,0.f};
        }
      #pragma unroll
      for (int kk = 0; kk < 4; ++kk) {
        bf16x8 a[4], bfr[2];
        #pragma unroll
        for (int mt = 0; mt < 4; ++mt) a[mt] = *(const bf16x8*)&sm.s1.xs[mt*16+i][kk*32+q*8];
        #pragma unroll
        for (int nt = 0; nt < 2; ++nt) bfr[nt] = *(const bf16x8*)&sm.s1.wsd[w*32+nt*16+i][kk*32+q*8];
        #pragma unroll
        for (int mt = 0; mt < 4; ++mt)
          #pragma unroll
          for (int nt = 0; nt < 2; ++nt)
            accv[mt][nt] = __builtin_amdgcn_mfma_f32_16x16x32_bf16(a[mt], bfr[nt], accv[mt][nt], 0, 0, 0);
      }
      __syncthreads();
      const short* Wgb = P.WT + 3*16384;
      for (int v = tid; v < 2048; v += 256) {
        const int n = v >> 4, c8 = (v & 15)*8;
        *(bf16x8*)&sm.s1.wsd[n][c8] = *(const bf16x8*)&Wgb[n*D_ + c8];
      }
      __syncthreads();
      #pragma unroll
      for (int kk = 0; kk < 4; ++kk) {
        bf16x8 a[4], bfr[2];
        #pragma unroll
        for (int mt = 0; mt < 4; ++mt) a[mt] = *(const bf16x8*)&sm.s1.xs[mt*16+i][kk*32+q*8];
        #pragma unroll
        for (int nt = 0; nt < 2; ++nt) bfr[nt] = *(const bf16x8*)&sm.s1.wsd[w*32+nt*16+i][kk*32+q*8];
        #pragma unroll
        for (int mt = 0; mt < 4; ++mt)
          #pragma unroll
          for (int nt = 0; nt < 2; ++nt)
            accg[mt][nt] = __builtin_amdgcn_mfma_f32_16x16x32_bf16(a[mt], bfr[nt], accg[mt][nt], 0, 0, 0);
      }
      #pragma unroll
      for (int mt = 0; mt < 4; ++mt)
        #pragma unroll
        for (int nt = 0; nt < 2; ++nt) {
          const int h = w*32 + nt*16 + i;
          const int t0 = m0 + mt*16 + 4*q;
          const float bgd = P.bg[h];
          bf16x4 o;
          #pragma unroll
          for (int r = 0; r < 4; ++r) {
            const float gv = 1.f/(1.f + __expf(-(accg[mt][nt][r] + bgd)));
            o[r] = f2bf(accv[mt][nt][r] * gv);
          }
          *(bf16x4*)&P.VgT[h*NTOK + t0] = o;
        }
    }
  }
  gbar(P.bar + 1);

  // ================= stage 2: per-chunk KV^T + Ksum ==========
  for (int u = bid; u < 256; u += gsz) {
    const int c = u >> 1, hh = u & 1;
    const int tb = c*CHUNK;
    __syncthreads();
    for (int v = tid; v < 1024; v += 256) {
      const int d = v >> 3, c8 = (v & 7)*8;
      *(bf16x8*)&sm.s2.vgl[d][c8] = *(const bf16x8*)&P.VgT[d*NTOK + tb + c8];
    }
    for (int v = tid; v < 512; v += 256) {
      const int h = v >> 3, c8 = (v & 7)*8;
      *(bf16x8*)&sm.s2.kpl[h][c8] = *(const bf16x8*)&P.KpT[(hh*64+h)*NTOK + tb + c8];
    }
    __syncthreads();
    f32x4 acc[2][4];
    #pragma unroll
    for (int mt = 0; mt < 2; ++mt)
      #pragma unroll
      for (int nt = 0; nt < 4; ++nt) acc[mt][nt] = (f32x4){0.f,0.f,0.f,0.f};
    #pragma unroll
    for (int kk = 0; kk < 2; ++kk) {
      bf16x8 a[2], bb[4];
      #pragma unroll
      for (int mt = 0; mt < 2; ++mt) a[mt] = *(const bf16x8*)&sm.s2.vgl[(2*w+mt)*16+i][kk*32+q*8];
      #pragma unroll
      for (int nt = 0; nt < 4; ++nt) bb[nt] = *(const bf16x8*)&sm.s2.kpl[nt*16+i][kk*32+q*8];
      #pragma unroll
      for (int mt = 0; mt < 2; ++mt)
        #pragma unroll
        for (int nt = 0; nt < 4; ++nt)
          acc[mt][nt] = __builtin_amdgcn_mfma_f32_16x16x32_bf16(a[mt], bb[nt], acc[mt][nt], 0, 0, 0);
    }
    float* KVc = P.KVT + (size_t)c*16384;
    #pragma unroll
    for (int mt = 0; mt < 2; ++mt)
      #pragma unroll
      for (int nt = 0; nt < 4; ++nt)
        #pragma unroll
        for (int r = 0; r < 4; ++r)
          KVc[((2*w+mt)*16 + 4*q + r)*D_ + hh*64 + nt*16 + i] = acc[mt][nt][r];
    {
      const int h = tid >> 2, part = tid & 3;
      float s = 0.f;
      #pragma unroll
      for (int t = 0; t < 16; ++t) s += bf2f(sm.s2.kpl[h][part*16 + t]);
      sm.s2.ksp[h][part] = s;
    }
    __syncthreads();
    if (tid < 64)
      P.Ksum[c*D_ + hh*64 + tid] = sm.s2.ksp[tid][0]+sm.s2.ksp[tid][1]+sm.s2.ksp[tid][2]+sm.s2.ksp[tid][3];
  }
  gbar(P.bar + 2);

  // ================= stage 3: exclusive chunk prefix ==========
  for (int u = bid; u < 129; u += gsz) {
    if (u < 128) {
      const int b = u >> 6;
      const int e = (u & 63)*256 + tid;
      const size_t base = (size_t)b*NCB*16384 + e;
      float run = 0.f;
      #pragma unroll 8
      for (int c = 0; c < NCB; ++c) {
        const float v = P.KVT[base + (size_t)c*16384];
        P.KVTb[base + (size_t)c*16384] = f2bf(run);
        run += v;
      }
    } else {
      const int b = tid >> 7, h = tid & 127;
      float run = 0.f;
      #pragma unroll 8
      for (int c = 0; c < NCB; ++c) {
        const int idx = (b*NCB + c)*D_ + h;
        const float v = P.Ksum[idx];
        P.Ksum[idx] = run;
        run += v;
      }
    }
  }
  gbar(P.bar + 3);

  // ================= stage 4: scores + attnout fused ==========
  for (int u = bid; u < 256; u += gsz) {
    const int c = u >> 1, dh = u & 1;
    const int tb = c*CHUNK;
    __syncthreads();
    for (int v = tid; v < 1024; v += 256) {
      const int t = v >> 4, c8 = (v & 15)*8;
      *(bf16x8*)&sm.s4.at[t][64 + c8] = *(const bf16x8*)&P.Qp[(tb+t)*D_ + c8];
      *(bf16x8*)&sm.s4.bt[t][c8]      = *(const bf16x8*)&P.Kp[(tb+t)*D_ + c8];
    }
    if (tid < 128) sm.s4.ksl[tid] = P.Ksum[c*D_ + tid];
    __syncthreads();
    {
      f32x4 acc[4];
      #pragma unroll
      for (int nt = 0; nt < 4; ++nt) acc[nt] = (f32x4){0.f,0.f,0.f,0.f};
      #pragma unroll
      for (int kk = 0; kk < 4; ++kk) {
        bf16x8 a = *(const bf16x8*)&sm.s4.at[w*16+i][64 + kk*32+q*8];
        for (int nt = 0; nt <= w; ++nt) {
          bf16x8 bb = *(const bf16x8*)&sm.s4.bt[nt*16+i][kk*32+q*8];
          acc[nt] = __builtin_amdgcn_mfma_f32_16x16x32_bf16(a, bb, acc[nt], 0, 0, 0);
        }
      }
      float rs[4] = {0.f,0.f,0.f,0.f};
      #pragma unroll
      for (int nt = 0; nt < 4; ++nt)
        #pragma unroll
        for (int r = 0; r < 4; ++r) {
          const int t = w*16 + 4*q + r;
          const int s = nt*16 + i;
          const float v = (nt <= w && s <= t) ? acc[nt][r] : 0.f;
          rs[r] += v;
          sm.s4.at[t][s] = f2bf(v);
        }
      #pragma unroll
      for (int r = 0; r < 4; ++r) {
        #pragma unroll
        for (int off = 1; off < 16; off <<= 1) rs[r] += __shfl_xor(rs[r], off);
      }
      if (i == 0) {
        #pragma unroll
        for (int r = 0; r < 4; ++r) sm.s4.rsl[w*16 + 4*q + r] = rs[r];
      }
    }
    {
      const int t = tid >> 2, part = tid & 3;
      float dot = 0.f;
      #pragma unroll
      for (int h = 0; h < 32; ++h)
        dot += bf2f(sm.s4.at[t][64 + part*32 + h]) * sm.s4.ksl[part*32 + h];
      sm.s4.dpart[t][part] = dot;
    }
    __syncthreads();
    if (tid < 64)
      sm.s4.denl[tid] = fmaxf(sm.s4.rsl[tid] + sm.s4.dpart[tid][0]+sm.s4.dpart[tid][1]
                              +sm.s4.dpart[tid][2]+sm.s4.dpart[tid][3], EPS_ATTN);
    for (int v = tid; v < 512; v += 256) {
      const int dd = v >> 3, c8 = (v & 7)*8;
      *(bf16x8*)&sm.s4.bt[dd][c8] = *(const bf16x8*)&P.VgT[(dh*64+dd)*NTOK + tb + c8];
    }
    for (int v = tid; v < 1024; v += 256) {
      const int dd = v >> 4, c8 = (v & 15)*8;
      *(bf16x8*)&sm.s4.bt[dd][64 + c8] = *(const bf16x8*)&P.KVTb[(size_t)c*16384 + (dh*64+dd)*D_ + c8];
    }
    __syncthreads();
    f32x4 acc2[4];
    #pragma unroll
    for (int nt = 0; nt < 4; ++nt) acc2[nt] = (f32x4){0.f,0.f,0.f,0.f};
    #pragma unroll
    for (int kk = 0; kk < 6; ++kk) {
      bf16x8 a = *(const bf16x8*)&sm.s4.at[w*16+i][kk*32+q*8];
      #pragma unroll
      for (int nt = 0; nt < 4; ++nt) {
        bf16x8 bb = *(const bf16x8*)&sm.s4.bt[nt*16+i][kk*32+q*8];
        acc2[nt] = __builtin_amdgcn_mfma_f32_16x16x32_bf16(a, bb, acc2[nt], 0, 0, 0);
      }
    }
    #pragma unroll
    for (int r = 0; r < 4; ++r) {
      const int t = w*16 + 4*q + r;
      const float inv = 1.f / sm.s4.denl[t];
      #pragma unroll
      for (int nt = 0; nt < 4; ++nt)
        P.attn[(size_t)(tb+t)*D_ + dh*64 + nt*16 + i] = f2bf(acc2[nt][r] * inv);
    }
  }
  gbar(P.bar + 4);

  // ================= stage 5: out = LN2(tokens + 0.1*(attn@Wo)) ==========
  for (int u = bid; u < 256; u += gsz) {
    const int m0 = u*32;
    __syncthreads();
    for (int v = tid; v < 512; v += 256) {
      const int t = v >> 4, c8 = (v & 15)*8;
      *(bf16x8*)&sm.s5.al[t][c8] = *(const bf16x8*)&P.attn[(m0+t)*D_ + c8];
    }
    const short* WoT = P.WT + 4*16384;
    for (int v = tid; v < 2048; v += 256) {
      const int n = v >> 4, c8 = (v & 15)*8;
      *(bf16x8*)&sm.s5.wl[n][c8] = *(const bf16x8*)&WoT[n*D_ + c8];
    }
    for (int v = tid; v < 1024; v += 256) {
      const int t = v >> 5, c4 = (v & 31)*4;
      *(float4*)&sm.s5.tl[t][c4] = *(const float4*)&P.tokens[(m0+t)*D_ + c4];
    }
    if (tid < 128) { sm.s5.gl[tid] = P.g2[tid]; sm.s5.bl2[tid] = P.b2[tid]; }
    __syncthreads();
    const int mt = w >> 1, nh = w & 1;
    f32x4 acc[4];
    #pragma unroll
    for (int j = 0; j < 4; ++j) acc[j] = (f32x4){0.f,0.f,0.f,0.f};
    #pragma unroll
    for (int kk = 0; kk < 4; ++kk) {
      bf16x8 a = *(const bf16x8*)&sm.s5.al[mt*16+i][kk*32+q*8];
      #pragma unroll
      for (int j = 0; j < 4; ++j) {
        bf16x8 bb = *(const bf16x8*)&sm.s5.wl[(nh*4+j)*16+i][kk*32+q*8];
        acc[j] = __builtin_amdgcn_mfma_f32_16x16x32_bf16(a, bb, acc[j], 0, 0, 0);
      }
    }
    float p[4][4], ps[4], qs[4];
    #pragma unroll
    for (int r = 0; r < 4; ++r) {
      const int t = mt*16 + 4*q + r;
      ps[r] = 0.f; qs[r] = 0.f;
      #pragma unroll
      for (int j = 0; j < 4; ++j) {
        const int col = nh*64 + j*16 + i;
        const float v = sm.s5.tl[t][col] + 0.1f*acc[j][r];
        p[r][j] = v; ps[r] += v; qs[r] += v*v;
      }
    }
    #pragma unroll
    for (int r = 0; r < 4; ++r) {
      #pragma unroll
      for (int off = 1; off < 16; off <<= 1) {
        ps[r] += __shfl_xor(ps[r], off);
        qs[r] += __shfl_xor(qs[r], off);
      }
    }
    if (i == 0) {
      #pragma unroll
      for (int r = 0; r < 4; ++r) {
        sm.s5.suml[mt*16+4*q+r][nh] = ps[r];
        sm.s5.ssql[mt*16+4*q+r][nh] = qs[r];
      }
    }
    __syncthreads();
    if (tid < 32) {
      const float s = sm.s5.suml[tid][0] + sm.s5.suml[tid][1];
      const float qq = sm.s5.ssql[tid][0] + sm.s5.ssql[tid][1];
      const float mean = s*(1.f/D_);
      sm.s5.meanl[tid] = mean;
      sm.s5.rstdl[tid] = rsqrtf(qq*(1.f/D_) - mean*mean + LN_EPS);
    }
    __syncthreads();
    #pragma unroll
    for (int r = 0; r < 4; ++r) {
      const int t = mt*16 + 4*q + r;
      const float mean = sm.s5.meanl[t], rr = sm.s5.rstdl[t];
      #pragma unroll
      for (int j = 0; j < 4; ++j) {
        const int col = nh*64 + j*16 + i;
        P.out[(m0+t)*D_ + col] = (p[r][j]-mean)*rr*sm.s5.gl[col] + sm.s5.bl2[col];
      }
    }
  }
}

extern "C" void kernel_launch(void* const* d_in, const int* in_sizes, int n_in,
                              void* d_out, int out_size, void* d_ws, size_t ws_size,
                              hipStream_t stream) {
  char* base = (char*)d_ws;
  Params P;
  P.tokens = (const float*)d_in[0];
  P.Wq = (const float*)d_in[1];  P.Wk = (const float*)d_in[2];
  P.Wv = (const float*)d_in[3];  P.Wg = (const float*)d_in[4];
  P.bg = (const float*)d_in[5];  P.Wo = (const float*)d_in[6];
  P.g1 = (const float*)d_in[7];  P.b1 = (const float*)d_in[8];
  P.g2 = (const float*)d_in[9];  P.b2 = (const float*)d_in[10];
  P.xb   = (short*)(base);                 // 2MB
  P.Qp   = (short*)(base + (2u<<20));      // 2MB
  P.Kp   = (short*)(base + (4u<<20));      // 2MB
  P.KpT  = (short*)(base + (6u<<20));      // 2MB
  P.VgT  = (short*)(base + (8u<<20));      // 2MB
  P.attn = (short*)(base + (10u<<20));     // 2MB
  P.KVTb = (short*)(base + (12u<<20));     // 4MB
  P.KVT  = (float*)(base + (16u<<20));     // 8MB
  P.WT   = (short*)(base + (24u<<20));     // 160KB
  P.Ksum = (float*)(base + (25u<<20));     // 64KB
  P.bar  = (unsigned*)(base + (25u<<20) + (128u<<10)); // 5 counters
  P.out  = (float*)d_out;

  hipMemsetAsync(P.bar, 0, 8*sizeof(unsigned), stream);
  mega<<<dim3(NBLK), dim3(256), 0, stream>>>(P);
}